// Round 6
// baseline (1752.559 us; speedup 1.0000x reference)
//
#include <hip/hip_runtime.h>
#include <math.h>

#define NDIMS 32
#define NANG 496          // 32*31/2
#define MPB 8             // matrices per gen_R block
#define WCOLS 256         // columns per block (64 lanes * f32x4)

typedef float f32x4 __attribute__((ext_vector_type(4)));

// ---------------- Kernel 1: build R^T (mus folded) into workspace ----------
// RTbuf[m][k][i] = mus[m][i] * R[i][k]   ([k][i] layout)
__global__ __launch_bounds__(256)
void gen_R(const float* __restrict__ angles, const float* __restrict__ mus,
           float* __restrict__ RT)
{
    __shared__ float2 cs[MPB][NANG];      // 31744 B
    const int tid = threadIdx.x;
    const int m0  = blockIdx.x * MPB;

    for (int idx = tid; idx < MPB * NANG; idx += 256) {
        const int lm = idx / NANG, a = idx - lm * NANG;
        float sv, cv;
        sincosf(angles[(size_t)(m0 + lm) * NANG + a], &sv, &cv);
        cs[lm][a] = make_float2(cv, sv);
    }
    __syncthreads();

    const int lm = tid >> 5, j = tid & 31;   // lane j owns column j of mat[m]
    const int m  = m0 + lm;

    float r[NDIMS];
    #pragma unroll
    for (int i = 0; i < NDIMS; ++i) r[i] = (i == j) ? 1.0f : 0.0f;

    int sidx = 0;
    #pragma unroll
    for (int t = 0; t < NDIMS - 1; ++t) {
        #pragma unroll
        for (int b = t + 1; b < NDIMS; ++b) {
            const float2 v = cs[lm][sidx]; ++sidx;   // compile-time sidx
            const float c = v.x, sn = v.y;
            const float vt = r[t], vb = r[b];
            const float u  = sn * (vt + vb);
            r[t] = (c + sn) * vt - u;
            r[b] = (c - sn) * vb + u;
        }
    }

    // RT[m][k=j][i] = r[i] * mu[i]
    float* dst = RT + (size_t)m * (NDIMS * NDIMS) + (size_t)j * NDIMS;
    const float* mu = mus + (size_t)m * NDIMS;
    #pragma unroll
    for (int i = 0; i < NDIMS; i += 4) {
        f32x4 v;
        v.x = r[i + 0] * mu[i + 0];
        v.y = r[i + 1] * mu[i + 1];
        v.z = r[i + 2] * mu[i + 2];
        v.w = r[i + 3] * mu[i + 3];
        *reinterpret_cast<f32x4*>(dst + i) = v;
    }
}

// ---------------- Kernel 2: out = R*x, wave-per-rowgroup GEMM tiling -------
// Block tile: 32 rows x 256 cols. Wave w owns rows [8w, 8w+8) x 256 cols.
// Per thread: 8 rows x 4 cols (acc = 32 VGPR). Per k: 8 R values at a
// wave-UNIFORM LDS address (free broadcast) + one unique 1KB x load.
// 8-deep k software pipeline -> 8KB outstanding reads/wave.
__global__ __launch_bounds__(256, 4)
void apply_R4(const float* __restrict__ x, const float* __restrict__ RT,
              float* __restrict__ out, int S)
{
    __shared__ float rt[NDIMS * NDIMS];   // [k][i], 4 KB
    const int tid = threadIdx.x;
    const int m   = blockIdx.x;

    *reinterpret_cast<f32x4*>(&rt[tid * 4]) =
        *reinterpret_cast<const f32x4*>(RT + (size_t)m * (NDIMS * NDIMS) + tid * 4);
    __syncthreads();

    const int igrp = tid >> 6;                 // wave id = row group (0..3)
    const int lane = tid & 63;
    const int i0   = igrp * 8;
    const int col  = blockIdx.y * WCOLS + lane * 4;

    const float* xp = x   + (size_t)m * NDIMS * S + col;
    float*       op = out + (size_t)m * NDIMS * S + col;

    f32x4 acc[8];
    #pragma unroll
    for (int r = 0; r < 8; ++r) acc[r] = (f32x4)0.0f;

    f32x4 xb[8];
    #pragma unroll
    for (int kk = 0; kk < 8; ++kk)
        xb[kk] = *reinterpret_cast<const f32x4*>(xp + (size_t)kk * S);

    #pragma unroll
    for (int kc = 0; kc < 4; ++kc) {
        f32x4 xn[8];
        if (kc < 3) {   // prefetch next 8 k-rows while computing current 8
            #pragma unroll
            for (int kk = 0; kk < 8; ++kk)
                xn[kk] = *reinterpret_cast<const f32x4*>(
                    xp + (size_t)((kc + 1) * 8 + kk) * S);
        }
        #pragma unroll
        for (int kk = 0; kk < 8; ++kk) {
            const int k = kc * 8 + kk;
            const f32x4 xv = xb[kk];
            // 8 R values, wave-uniform address -> 2x uniform ds_read_b128
            const f32x4 ra = *reinterpret_cast<const f32x4*>(&rt[k * NDIMS + i0]);
            const f32x4 rb = *reinterpret_cast<const f32x4*>(&rt[k * NDIMS + i0 + 4]);
            #pragma unroll
            for (int r = 0; r < 4; ++r) {
                const float rv = (r == 0) ? ra.x : (r == 1) ? ra.y : (r == 2) ? ra.z : ra.w;
                acc[r].x = fmaf(rv, xv.x, acc[r].x);
                acc[r].y = fmaf(rv, xv.y, acc[r].y);
                acc[r].z = fmaf(rv, xv.z, acc[r].z);
                acc[r].w = fmaf(rv, xv.w, acc[r].w);
            }
            #pragma unroll
            for (int r = 0; r < 4; ++r) {
                const float rv = (r == 0) ? rb.x : (r == 1) ? rb.y : (r == 2) ? rb.z : rb.w;
                acc[r + 4].x = fmaf(rv, xv.x, acc[r + 4].x);
                acc[r + 4].y = fmaf(rv, xv.y, acc[r + 4].y);
                acc[r + 4].z = fmaf(rv, xv.z, acc[r + 4].z);
                acc[r + 4].w = fmaf(rv, xv.w, acc[r + 4].w);
            }
        }
        if (kc < 3) {
            #pragma unroll
            for (int kk = 0; kk < 8; ++kk) xb[kk] = xn[kk];
        }
    }

    #pragma unroll
    for (int r = 0; r < 8; ++r)
        *reinterpret_cast<f32x4*>(op + (size_t)(i0 + r) * S) = acc[r];
}

// ---------------- Fallback: fused kernel (odd sizes / tiny ws) -------------
#define RT_STRIDE 36
__global__ __launch_bounds__(256, 4)
void soot_fused(const float* __restrict__ x, const float* __restrict__ angles,
                const float* __restrict__ mus, float* __restrict__ out, int S)
{
    __shared__ float2 cs[NANG];
    __shared__ float  RT[NDIMS * RT_STRIDE];
    const int tid = threadIdx.x;
    const int m   = blockIdx.x;

    for (int s0 = tid; s0 < NANG; s0 += 256) {
        float sv, cv;
        sincosf(angles[(size_t)m * NANG + s0], &sv, &cv);
        cs[s0] = make_float2(cv, sv);
    }
    __syncthreads();

    if (tid < NDIMS) {
        const int j = tid;
        float r[NDIMS];
        #pragma unroll
        for (int i = 0; i < NDIMS; ++i) r[i] = (i == j) ? 1.0f : 0.0f;
        int sidx = 0;
        #pragma unroll
        for (int t = 0; t < NDIMS - 1; ++t)
            #pragma unroll
            for (int b = t + 1; b < NDIMS; ++b) {
                const float2 v = cs[sidx]; ++sidx;
                const float c = v.x, sn = v.y;
                const float vt = r[t], vb = r[b];
                const float u  = sn * (vt + vb);
                r[t] = (c + sn) * vt - u;
                r[b] = (c - sn) * vb + u;
            }
        #pragma unroll
        for (int i = 0; i < NDIMS; ++i)
            RT[j * RT_STRIDE + i] = r[i] * mus[(size_t)m * NDIMS + i];
    }
    __syncthreads();

    for (int c0 = tid; c0 < S; c0 += 256) {
        float acc[NDIMS];
        #pragma unroll
        for (int i = 0; i < NDIMS; ++i) acc[i] = 0.f;
        #pragma unroll
        for (int k = 0; k < NDIMS; ++k) {
            const float xv = x[(size_t)m * NDIMS * S + (size_t)k * S + c0];
            #pragma unroll
            for (int i = 0; i < NDIMS; ++i)
                acc[i] = fmaf(RT[k * RT_STRIDE + i], xv, acc[i]);
        }
        #pragma unroll
        for (int i = 0; i < NDIMS; ++i)
            out[(size_t)m * NDIMS * S + (size_t)i * S + c0] = acc[i];
    }
}

extern "C" void kernel_launch(void* const* d_in, const int* in_sizes, int n_in,
                              void* d_out, int out_size, void* d_ws, size_t ws_size,
                              hipStream_t stream) {
    const float* x      = (const float*)d_in[0];
    const float* angles = (const float*)d_in[1];
    const float* mus    = (const float*)d_in[2];
    float* out          = (float*)d_out;

    const int M = in_sizes[1] / NANG;              // 1024
    const int S = in_sizes[0] / (M * NDIMS);       // 2048

    const size_t rt_bytes = (size_t)M * NDIMS * NDIMS * sizeof(float);  // 4 MB
    if (ws_size >= rt_bytes && (M % MPB) == 0 && (S % WCOLS) == 0) {
        float* RT = (float*)d_ws;
        gen_R<<<dim3(M / MPB), 256, 0, stream>>>(angles, mus, RT);
        dim3 grid(M, S / WCOLS);
        apply_R4<<<grid, 256, 0, stream>>>(x, RT, out, S);
    } else {
        soot_fused<<<dim3(M), 256, 0, stream>>>(x, angles, mus, out, S);
    }
}

// Round 7
// 509.875 us; speedup vs baseline: 3.4372x; 3.4372x over previous
//
#include <hip/hip_runtime.h>
#include <math.h>

#define NDIMS 32
#define NANG 496          // 32*31/2
#define MPB 8             // matrices per gen_R block
#define WCOLS 256         // columns per block (64 lanes * f32x4)

typedef float f32x4 __attribute__((ext_vector_type(4)));

// ---------------- Kernel 1: build R^T (mus folded) into workspace ----------
// RTbuf[m][k][i] = mus[m][i] * R[i][k]   ([k][i] layout)
__global__ __launch_bounds__(256)
void gen_R(const float* __restrict__ angles, const float* __restrict__ mus,
           float* __restrict__ RT)
{
    __shared__ float2 cs[MPB][NANG];      // 31744 B
    const int tid = threadIdx.x;
    const int m0  = blockIdx.x * MPB;

    for (int idx = tid; idx < MPB * NANG; idx += 256) {
        const int lm = idx / NANG, a = idx - lm * NANG;
        float sv, cv;
        sincosf(angles[(size_t)(m0 + lm) * NANG + a], &sv, &cv);
        cs[lm][a] = make_float2(cv, sv);
    }
    __syncthreads();

    const int lm = tid >> 5, j = tid & 31;   // lane j owns column j of mat[m]
    const int m  = m0 + lm;

    float r[NDIMS];
    #pragma unroll
    for (int i = 0; i < NDIMS; ++i) r[i] = (i == j) ? 1.0f : 0.0f;

    int sidx = 0;
    #pragma unroll
    for (int t = 0; t < NDIMS - 1; ++t) {
        #pragma unroll
        for (int b = t + 1; b < NDIMS; ++b) {
            const float2 v = cs[lm][sidx]; ++sidx;   // compile-time sidx
            const float c = v.x, sn = v.y;
            const float vt = r[t], vb = r[b];
            const float u  = sn * (vt + vb);
            r[t] = (c + sn) * vt - u;
            r[b] = (c - sn) * vb + u;
        }
    }

    // RT[m][k=j][i] = r[i] * mu[i]
    float* dst = RT + (size_t)m * (NDIMS * NDIMS) + (size_t)j * NDIMS;
    const float* mu = mus + (size_t)m * NDIMS;
    #pragma unroll
    for (int i = 0; i < NDIMS; i += 4) {
        f32x4 v;
        v.x = r[i + 0] * mu[i + 0];
        v.y = r[i + 1] * mu[i + 1];
        v.z = r[i + 2] * mu[i + 2];
        v.w = r[i + 3] * mu[i + 3];
        *reinterpret_cast<f32x4*>(dst + i) = v;
    }
}

// ---------------- Kernel 2: out = R*x, wave-per-rowgroup GEMM tiling -------
// Block tile: 32 rows x 256 cols. Wave w owns rows [8w, 8w+8) x 256 cols.
// Per thread: 8 rows x 4 cols (acc = 32 VGPR). Per k: 8 R values at a
// wave-UNIFORM LDS address (free broadcast) + one unique 1KB x load.
// 8-deep k software pipeline -> 8KB outstanding reads/wave.
// NOTE: min-waves hint = 2 (NOT 4): the 4-floor capped VGPR at 64 and
// spilled xb/xn/acc to scratch -> 7.3 GB of HBM spill traffic (R6).
__global__ __launch_bounds__(256, 2)
void apply_R4(const float* __restrict__ x, const float* __restrict__ RT,
              float* __restrict__ out, int S)
{
    __shared__ float rt[NDIMS * NDIMS];   // [k][i], 4 KB
    const int tid = threadIdx.x;
    const int m   = blockIdx.x;

    *reinterpret_cast<f32x4*>(&rt[tid * 4]) =
        *reinterpret_cast<const f32x4*>(RT + (size_t)m * (NDIMS * NDIMS) + tid * 4);
    __syncthreads();

    const int igrp = tid >> 6;                 // wave id = row group (0..3)
    const int lane = tid & 63;
    const int i0   = igrp * 8;
    const int col  = blockIdx.y * WCOLS + lane * 4;

    const float* xp = x   + (size_t)m * NDIMS * S + col;
    float*       op = out + (size_t)m * NDIMS * S + col;

    f32x4 acc[8];
    #pragma unroll
    for (int r = 0; r < 8; ++r) acc[r] = (f32x4)0.0f;

    f32x4 xb[8];
    #pragma unroll
    for (int kk = 0; kk < 8; ++kk)
        xb[kk] = *reinterpret_cast<const f32x4*>(xp + (size_t)kk * S);

    #pragma unroll
    for (int kc = 0; kc < 4; ++kc) {
        f32x4 xn[8];
        if (kc < 3) {   // prefetch next 8 k-rows while computing current 8
            #pragma unroll
            for (int kk = 0; kk < 8; ++kk)
                xn[kk] = *reinterpret_cast<const f32x4*>(
                    xp + (size_t)((kc + 1) * 8 + kk) * S);
        }
        #pragma unroll
        for (int kk = 0; kk < 8; ++kk) {
            const int k = kc * 8 + kk;
            const f32x4 xv = xb[kk];
            // 8 R values, wave-uniform address -> 2x uniform ds_read_b128
            const f32x4 ra = *reinterpret_cast<const f32x4*>(&rt[k * NDIMS + i0]);
            const f32x4 rb = *reinterpret_cast<const f32x4*>(&rt[k * NDIMS + i0 + 4]);
            #pragma unroll
            for (int r = 0; r < 4; ++r) {
                const float rv = (r == 0) ? ra.x : (r == 1) ? ra.y : (r == 2) ? ra.z : ra.w;
                acc[r].x = fmaf(rv, xv.x, acc[r].x);
                acc[r].y = fmaf(rv, xv.y, acc[r].y);
                acc[r].z = fmaf(rv, xv.z, acc[r].z);
                acc[r].w = fmaf(rv, xv.w, acc[r].w);
            }
            #pragma unroll
            for (int r = 0; r < 4; ++r) {
                const float rv = (r == 0) ? rb.x : (r == 1) ? rb.y : (r == 2) ? rb.z : rb.w;
                acc[r + 4].x = fmaf(rv, xv.x, acc[r + 4].x);
                acc[r + 4].y = fmaf(rv, xv.y, acc[r + 4].y);
                acc[r + 4].z = fmaf(rv, xv.z, acc[r + 4].z);
                acc[r + 4].w = fmaf(rv, xv.w, acc[r + 4].w);
            }
        }
        if (kc < 3) {
            #pragma unroll
            for (int kk = 0; kk < 8; ++kk) xb[kk] = xn[kk];
        }
    }

    #pragma unroll
    for (int r = 0; r < 8; ++r)
        *reinterpret_cast<f32x4*>(op + (size_t)(i0 + r) * S) = acc[r];
}

// ---------------- Fallback: fused kernel (odd sizes / tiny ws) -------------
#define RT_STRIDE 36
__global__ __launch_bounds__(256, 4)
void soot_fused(const float* __restrict__ x, const float* __restrict__ angles,
                const float* __restrict__ mus, float* __restrict__ out, int S)
{
    __shared__ float2 cs[NANG];
    __shared__ float  RT[NDIMS * RT_STRIDE];
    const int tid = threadIdx.x;
    const int m   = blockIdx.x;

    for (int s0 = tid; s0 < NANG; s0 += 256) {
        float sv, cv;
        sincosf(angles[(size_t)m * NANG + s0], &sv, &cv);
        cs[s0] = make_float2(cv, sv);
    }
    __syncthreads();

    if (tid < NDIMS) {
        const int j = tid;
        float r[NDIMS];
        #pragma unroll
        for (int i = 0; i < NDIMS; ++i) r[i] = (i == j) ? 1.0f : 0.0f;
        int sidx = 0;
        #pragma unroll
        for (int t = 0; t < NDIMS - 1; ++t)
            #pragma unroll
            for (int b = t + 1; b < NDIMS; ++b) {
                const float2 v = cs[sidx]; ++sidx;
                const float c = v.x, sn = v.y;
                const float vt = r[t], vb = r[b];
                const float u  = sn * (vt + vb);
                r[t] = (c + sn) * vt - u;
                r[b] = (c - sn) * vb + u;
            }
        #pragma unroll
        for (int i = 0; i < NDIMS; ++i)
            RT[j * RT_STRIDE + i] = r[i] * mus[(size_t)m * NDIMS + i];
    }
    __syncthreads();

    for (int c0 = tid; c0 < S; c0 += 256) {
        float acc[NDIMS];
        #pragma unroll
        for (int i = 0; i < NDIMS; ++i) acc[i] = 0.f;
        #pragma unroll
        for (int k = 0; k < NDIMS; ++k) {
            const float xv = x[(size_t)m * NDIMS * S + (size_t)k * S + c0];
            #pragma unroll
            for (int i = 0; i < NDIMS; ++i)
                acc[i] = fmaf(RT[k * RT_STRIDE + i], xv, acc[i]);
        }
        #pragma unroll
        for (int i = 0; i < NDIMS; ++i)
            out[(size_t)m * NDIMS * S + (size_t)i * S + c0] = acc[i];
    }
}

extern "C" void kernel_launch(void* const* d_in, const int* in_sizes, int n_in,
                              void* d_out, int out_size, void* d_ws, size_t ws_size,
                              hipStream_t stream) {
    const float* x      = (const float*)d_in[0];
    const float* angles = (const float*)d_in[1];
    const float* mus    = (const float*)d_in[2];
    float* out          = (float*)d_out;

    const int M = in_sizes[1] / NANG;              // 1024
    const int S = in_sizes[0] / (M * NDIMS);       // 2048

    const size_t rt_bytes = (size_t)M * NDIMS * NDIMS * sizeof(float);  // 4 MB
    if (ws_size >= rt_bytes && (M % MPB) == 0 && (S % WCOLS) == 0) {
        float* RT = (float*)d_ws;
        gen_R<<<dim3(M / MPB), 256, 0, stream>>>(angles, mus, RT);
        dim3 grid(M, S / WCOLS);
        apply_R4<<<grid, 256, 0, stream>>>(x, RT, out, S);
    } else {
        soot_fused<<<dim3(M), 256, 0, stream>>>(x, angles, mus, out, S);
    }
}

// Round 8
// 223.213 us; speedup vs baseline: 7.8515x; 2.2842x over previous
//
#include <hip/hip_runtime.h>
#include <math.h>

#define NDIMS 32
#define NANG 496          // 32*31/2
#define MPB 8             // matrices per gen_R block
#define WCOLS 256         // columns per block (64 lanes * f32x4)

typedef float f32x4 __attribute__((ext_vector_type(4)));

// ---------------- Kernel 1: build R^T (mus folded) into workspace ----------
// RTbuf[m][k][i] = mus[m][i] * R[i][k]   ([k][i] layout)
__global__ __launch_bounds__(256)
void gen_R(const float* __restrict__ angles, const float* __restrict__ mus,
           float* __restrict__ RT)
{
    __shared__ float2 cs[MPB][NANG];      // 31744 B
    const int tid = threadIdx.x;
    const int m0  = blockIdx.x * MPB;

    for (int idx = tid; idx < MPB * NANG; idx += 256) {
        const int lm = idx / NANG, a = idx - lm * NANG;
        float sv, cv;
        sincosf(angles[(size_t)(m0 + lm) * NANG + a], &sv, &cv);
        cs[lm][a] = make_float2(cv, sv);
    }
    __syncthreads();

    const int lm = tid >> 5, j = tid & 31;   // lane j owns column j of mat[m]
    const int m  = m0 + lm;

    float r[NDIMS];
    #pragma unroll
    for (int i = 0; i < NDIMS; ++i) r[i] = (i == j) ? 1.0f : 0.0f;

    int sidx = 0;
    #pragma unroll
    for (int t = 0; t < NDIMS - 1; ++t) {
        #pragma unroll
        for (int b = t + 1; b < NDIMS; ++b) {
            const float2 v = cs[lm][sidx]; ++sidx;   // compile-time sidx
            const float c = v.x, sn = v.y;
            const float vt = r[t], vb = r[b];
            const float u  = sn * (vt + vb);
            r[t] = (c + sn) * vt - u;
            r[b] = (c - sn) * vb + u;
        }
    }

    // RT[m][k=j][i] = r[i] * mu[i]
    float* dst = RT + (size_t)m * (NDIMS * NDIMS) + (size_t)j * NDIMS;
    const float* mu = mus + (size_t)m * NDIMS;
    #pragma unroll
    for (int i = 0; i < NDIMS; i += 4) {
        f32x4 v;
        v.x = r[i + 0] * mu[i + 0];
        v.y = r[i + 1] * mu[i + 1];
        v.z = r[i + 2] * mu[i + 2];
        v.w = r[i + 3] * mu[i + 3];
        *reinterpret_cast<f32x4*>(dst + i) = v;
    }
}

// ---------------- Kernel 2: out = R*x, wave-per-rowgroup GEMM tiling -------
// Block tile: 32 rows x 256 cols. Wave w owns rows [8w, 8w+8) x 256 cols.
// Per thread: 8 rows x 4 cols (acc = 32 VGPR). Per k: 8 R values at a
// wave-UNIFORM LDS address (2 broadcast ds_read_b128) + one unique 1KB x load.
// Pipeline depth 4 (cur/nxt) => 64 data VGPRs; NO min-waves hint: R6 (floor 4
// -> 64 VGPR cap) and R7 (floor 2 -> 128 cap) both spilled to scratch, 7.3 GB
// and 1.5 GB of HBM spill traffic respectively. Let the allocator size itself.
__global__ __launch_bounds__(256)
void apply_R5(const float* __restrict__ x, const float* __restrict__ RT,
              float* __restrict__ out, int S)
{
    __shared__ float rt[NDIMS * NDIMS];   // [k][i], 4 KB
    const int tid = threadIdx.x;
    const int m   = blockIdx.x;

    *reinterpret_cast<f32x4*>(&rt[tid * 4]) =
        *reinterpret_cast<const f32x4*>(RT + (size_t)m * (NDIMS * NDIMS) + tid * 4);
    __syncthreads();

    const int igrp = tid >> 6;                 // wave id = row group (0..3)
    const int lane = tid & 63;
    const int i0   = igrp * 8;
    const int col  = blockIdx.y * WCOLS + lane * 4;

    const float* xp = x   + (size_t)m * NDIMS * S + col;
    float*       op = out + (size_t)m * NDIMS * S + col;

    f32x4 acc[8];
    #pragma unroll
    for (int r = 0; r < 8; ++r) acc[r] = (f32x4)0.0f;

    // prologue: chunk 0 (k = 0..3)
    f32x4 cur[4];
    #pragma unroll
    for (int kk = 0; kk < 4; ++kk)
        cur[kk] = *reinterpret_cast<const f32x4*>(xp + (size_t)kk * S);

    #pragma unroll
    for (int kc = 0; kc < 8; ++kc) {
        f32x4 nxt[4];
        if (kc < 7) {   // prefetch next 4 k-rows while computing current 4
            #pragma unroll
            for (int kk = 0; kk < 4; ++kk)
                nxt[kk] = *reinterpret_cast<const f32x4*>(
                    xp + (size_t)((kc + 1) * 4 + kk) * S);
        }
        #pragma unroll
        for (int kk = 0; kk < 4; ++kk) {
            const int k = kc * 4 + kk;
            const f32x4 xv = cur[kk];
            const f32x4 ra = *reinterpret_cast<const f32x4*>(&rt[k * NDIMS + i0]);
            const f32x4 rb = *reinterpret_cast<const f32x4*>(&rt[k * NDIMS + i0 + 4]);
            #pragma unroll
            for (int r = 0; r < 4; ++r) {
                const float rv = (r == 0) ? ra.x : (r == 1) ? ra.y : (r == 2) ? ra.z : ra.w;
                acc[r].x = fmaf(rv, xv.x, acc[r].x);
                acc[r].y = fmaf(rv, xv.y, acc[r].y);
                acc[r].z = fmaf(rv, xv.z, acc[r].z);
                acc[r].w = fmaf(rv, xv.w, acc[r].w);
            }
            #pragma unroll
            for (int r = 0; r < 4; ++r) {
                const float rv = (r == 0) ? rb.x : (r == 1) ? rb.y : (r == 2) ? rb.z : rb.w;
                acc[r + 4].x = fmaf(rv, xv.x, acc[r + 4].x);
                acc[r + 4].y = fmaf(rv, xv.y, acc[r + 4].y);
                acc[r + 4].z = fmaf(rv, xv.z, acc[r + 4].z);
                acc[r + 4].w = fmaf(rv, xv.w, acc[r + 4].w);
            }
        }
        if (kc < 7) {
            #pragma unroll
            for (int kk = 0; kk < 4; ++kk) cur[kk] = nxt[kk];
        }
    }

    #pragma unroll
    for (int r = 0; r < 8; ++r)
        *reinterpret_cast<f32x4*>(op + (size_t)(i0 + r) * S) = acc[r];
}

// ---------------- Fallback: fused kernel (odd sizes / tiny ws) -------------
#define RT_STRIDE 36
__global__ __launch_bounds__(256, 4)
void soot_fused(const float* __restrict__ x, const float* __restrict__ angles,
                const float* __restrict__ mus, float* __restrict__ out, int S)
{
    __shared__ float2 cs[NANG];
    __shared__ float  RT[NDIMS * RT_STRIDE];
    const int tid = threadIdx.x;
    const int m   = blockIdx.x;

    for (int s0 = tid; s0 < NANG; s0 += 256) {
        float sv, cv;
        sincosf(angles[(size_t)m * NANG + s0], &sv, &cv);
        cs[s0] = make_float2(cv, sv);
    }
    __syncthreads();

    if (tid < NDIMS) {
        const int j = tid;
        float r[NDIMS];
        #pragma unroll
        for (int i = 0; i < NDIMS; ++i) r[i] = (i == j) ? 1.0f : 0.0f;
        int sidx = 0;
        #pragma unroll
        for (int t = 0; t < NDIMS - 1; ++t)
            #pragma unroll
            for (int b = t + 1; b < NDIMS; ++b) {
                const float2 v = cs[sidx]; ++sidx;
                const float c = v.x, sn = v.y;
                const float vt = r[t], vb = r[b];
                const float u  = sn * (vt + vb);
                r[t] = (c + sn) * vt - u;
                r[b] = (c - sn) * vb + u;
            }
        #pragma unroll
        for (int i = 0; i < NDIMS; ++i)
            RT[j * RT_STRIDE + i] = r[i] * mus[(size_t)m * NDIMS + i];
    }
    __syncthreads();

    for (int c0 = tid; c0 < S; c0 += 256) {
        float acc[NDIMS];
        #pragma unroll
        for (int i = 0; i < NDIMS; ++i) acc[i] = 0.f;
        #pragma unroll
        for (int k = 0; k < NDIMS; ++k) {
            const float xv = x[(size_t)m * NDIMS * S + (size_t)k * S + c0];
            #pragma unroll
            for (int i = 0; i < NDIMS; ++i)
                acc[i] = fmaf(RT[k * RT_STRIDE + i], xv, acc[i]);
        }
        #pragma unroll
        for (int i = 0; i < NDIMS; ++i)
            out[(size_t)m * NDIMS * S + (size_t)i * S + c0] = acc[i];
    }
}

extern "C" void kernel_launch(void* const* d_in, const int* in_sizes, int n_in,
                              void* d_out, int out_size, void* d_ws, size_t ws_size,
                              hipStream_t stream) {
    const float* x      = (const float*)d_in[0];
    const float* angles = (const float*)d_in[1];
    const float* mus    = (const float*)d_in[2];
    float* out          = (float*)d_out;

    const int M = in_sizes[1] / NANG;              // 1024
    const int S = in_sizes[0] / (M * NDIMS);       // 2048

    const size_t rt_bytes = (size_t)M * NDIMS * NDIMS * sizeof(float);  // 4 MB
    if (ws_size >= rt_bytes && (M % MPB) == 0 && (S % WCOLS) == 0) {
        float* RT = (float*)d_ws;
        gen_R<<<dim3(M / MPB), 256, 0, stream>>>(angles, mus, RT);
        dim3 grid(M, S / WCOLS);
        apply_R5<<<grid, 256, 0, stream>>>(x, RT, out, S);
    } else {
        soot_fused<<<dim3(M), 256, 0, stream>>>(x, angles, mus, out, S);
    }
}

// Round 9
// 214.934 us; speedup vs baseline: 8.1540x; 1.0385x over previous
//
#include <hip/hip_runtime.h>
#include <math.h>

#define NDIMS 32
#define NANG 496          // 32*31/2
#define MPB 8             // matrices per gen_R block
#define WCOLS 256         // columns per block (64 lanes * f32x4)

typedef float f32x4 __attribute__((ext_vector_type(4)));

// ---------------- Kernel 1: build R^T (mus folded) into workspace ----------
// RTbuf[m][k][i] = mus[m][i] * R[i][k]   ([k][i] layout)
__global__ __launch_bounds__(256)
void gen_R(const float* __restrict__ angles, const float* __restrict__ mus,
           float* __restrict__ RT)
{
    __shared__ float2 cs[MPB][NANG];      // 31744 B
    const int tid = threadIdx.x;
    const int m0  = blockIdx.x * MPB;

    for (int idx = tid; idx < MPB * NANG; idx += 256) {
        const int lm = idx / NANG, a = idx - lm * NANG;
        float sv, cv;
        sincosf(angles[(size_t)(m0 + lm) * NANG + a], &sv, &cv);
        cs[lm][a] = make_float2(cv, sv);
    }
    __syncthreads();

    const int lm = tid >> 5, j = tid & 31;   // lane j owns column j of mat[m]
    const int m  = m0 + lm;

    float r[NDIMS];
    #pragma unroll
    for (int i = 0; i < NDIMS; ++i) r[i] = (i == j) ? 1.0f : 0.0f;

    int sidx = 0;
    #pragma unroll
    for (int t = 0; t < NDIMS - 1; ++t) {
        #pragma unroll
        for (int b = t + 1; b < NDIMS; ++b) {
            const float2 v = cs[lm][sidx]; ++sidx;   // compile-time sidx
            const float c = v.x, sn = v.y;
            const float vt = r[t], vb = r[b];
            const float u  = sn * (vt + vb);
            r[t] = (c + sn) * vt - u;
            r[b] = (c - sn) * vb + u;
        }
    }

    // RT[m][k=j][i] = r[i] * mu[i]
    float* dst = RT + (size_t)m * (NDIMS * NDIMS) + (size_t)j * NDIMS;
    const float* mu = mus + (size_t)m * NDIMS;
    #pragma unroll
    for (int i = 0; i < NDIMS; i += 4) {
        f32x4 v;
        v.x = r[i + 0] * mu[i + 0];
        v.y = r[i + 1] * mu[i + 1];
        v.z = r[i + 2] * mu[i + 2];
        v.w = r[i + 3] * mu[i + 3];
        *reinterpret_cast<f32x4*>(dst + i) = v;
    }
}

// ---------------- Kernel 2: out = R*x, wave-per-rowgroup GEMM tiling -------
// Block tile: 32 rows x 256 cols; wave w owns rows [8w,8w+8). Per thread:
// 8 rows x 4 cols (acc = 32 VGPR), 4-deep k double-buffer (cur/nxt = 32).
// ADDRESSING IS THE POINT (R8 post-mortem: per-thread 64-bit pointers ->
// 32 materialized vector addresses -> VGPR=184 -> 11% occupancy):
//   * x/out bases are WAVE-UNIFORM expressions (m, k, i0 uniform) -> SGPR
//   * only colOff (lane*4) is divergent -> single 32-bit voffset VGPR
//   * i0 forced uniform via readfirstlane so store bases are scalar too
//   * rt[] reads: one LDS addr VGPR + 16-bit offset immediates (<= 4092)
__global__ __launch_bounds__(256)
void apply_R6(const float* __restrict__ x, const float* __restrict__ RT,
              float* __restrict__ out, int S)
{
    __shared__ float rt[NDIMS * NDIMS];   // [k][i], 4 KB
    const int tid = threadIdx.x;
    const int m   = blockIdx.x;

    *reinterpret_cast<f32x4*>(&rt[tid * 4]) =
        *reinterpret_cast<const f32x4*>(RT + (size_t)m * (NDIMS * NDIMS) + tid * 4);
    __syncthreads();

    const int i0   = __builtin_amdgcn_readfirstlane((tid >> 6) * 8); // SGPR row base
    const int lane = tid & 63;
    const int colOff = blockIdx.y * WCOLS + lane * 4;   // divergent 32-bit offset

    const float* __restrict__ xm = x   + (size_t)m * NDIMS * S;  // uniform base
    float*       __restrict__ om = out + (size_t)m * NDIMS * S;  // uniform base

    f32x4 acc[8];
    #pragma unroll
    for (int r = 0; r < 8; ++r) acc[r] = (f32x4)0.0f;

    // prologue: chunk 0 (k = 0..3); each load = uniform(base + k*S) + colOff
    f32x4 cur[4];
    #pragma unroll
    for (int kk = 0; kk < 4; ++kk)
        cur[kk] = *reinterpret_cast<const f32x4*>(xm + (size_t)kk * S + colOff);

    #pragma unroll
    for (int kc = 0; kc < 8; ++kc) {
        f32x4 nxt[4];
        if (kc < 7) {   // prefetch next 4 k-rows while computing current 4
            #pragma unroll
            for (int kk = 0; kk < 4; ++kk)
                nxt[kk] = *reinterpret_cast<const f32x4*>(
                    xm + (size_t)((kc + 1) * 4 + kk) * S + colOff);
        }
        #pragma unroll
        for (int kk = 0; kk < 4; ++kk) {
            const int k = kc * 4 + kk;
            const f32x4 xv = cur[kk];
            const f32x4 ra = *reinterpret_cast<const f32x4*>(&rt[k * NDIMS + i0]);
            const f32x4 rb = *reinterpret_cast<const f32x4*>(&rt[k * NDIMS + i0 + 4]);
            #pragma unroll
            for (int r = 0; r < 4; ++r) {
                const float rv = (r == 0) ? ra.x : (r == 1) ? ra.y : (r == 2) ? ra.z : ra.w;
                acc[r].x = fmaf(rv, xv.x, acc[r].x);
                acc[r].y = fmaf(rv, xv.y, acc[r].y);
                acc[r].z = fmaf(rv, xv.z, acc[r].z);
                acc[r].w = fmaf(rv, xv.w, acc[r].w);
            }
            #pragma unroll
            for (int r = 0; r < 4; ++r) {
                const float rv = (r == 0) ? rb.x : (r == 1) ? rb.y : (r == 2) ? rb.z : rb.w;
                acc[r + 4].x = fmaf(rv, xv.x, acc[r + 4].x);
                acc[r + 4].y = fmaf(rv, xv.y, acc[r + 4].y);
                acc[r + 4].z = fmaf(rv, xv.z, acc[r + 4].z);
                acc[r + 4].w = fmaf(rv, xv.w, acc[r + 4].w);
            }
        }
        if (kc < 7) {
            #pragma unroll
            for (int kk = 0; kk < 4; ++kk) cur[kk] = nxt[kk];
        }
    }

    // stores: uniform(om + (i0+r)*S) + colOff
    #pragma unroll
    for (int r = 0; r < 8; ++r)
        *reinterpret_cast<f32x4*>(om + (size_t)(i0 + r) * S + colOff) = acc[r];
}

// ---------------- Fallback: fused kernel (odd sizes / tiny ws) -------------
#define RT_STRIDE 36
__global__ __launch_bounds__(256, 4)
void soot_fused(const float* __restrict__ x, const float* __restrict__ angles,
                const float* __restrict__ mus, float* __restrict__ out, int S)
{
    __shared__ float2 cs[NANG];
    __shared__ float  RT[NDIMS * RT_STRIDE];
    const int tid = threadIdx.x;
    const int m   = blockIdx.x;

    for (int s0 = tid; s0 < NANG; s0 += 256) {
        float sv, cv;
        sincosf(angles[(size_t)m * NANG + s0], &sv, &cv);
        cs[s0] = make_float2(cv, sv);
    }
    __syncthreads();

    if (tid < NDIMS) {
        const int j = tid;
        float r[NDIMS];
        #pragma unroll
        for (int i = 0; i < NDIMS; ++i) r[i] = (i == j) ? 1.0f : 0.0f;
        int sidx = 0;
        #pragma unroll
        for (int t = 0; t < NDIMS - 1; ++t)
            #pragma unroll
            for (int b = t + 1; b < NDIMS; ++b) {
                const float2 v = cs[sidx]; ++sidx;
                const float c = v.x, sn = v.y;
                const float vt = r[t], vb = r[b];
                const float u  = sn * (vt + vb);
                r[t] = (c + sn) * vt - u;
                r[b] = (c - sn) * vb + u;
            }
        #pragma unroll
        for (int i = 0; i < NDIMS; ++i)
            RT[j * RT_STRIDE + i] = r[i] * mus[(size_t)m * NDIMS + i];
    }
    __syncthreads();

    for (int c0 = tid; c0 < S; c0 += 256) {
        float acc[NDIMS];
        #pragma unroll
        for (int i = 0; i < NDIMS; ++i) acc[i] = 0.f;
        #pragma unroll
        for (int k = 0; k < NDIMS; ++k) {
            const float xv = x[(size_t)m * NDIMS * S + (size_t)k * S + c0];
            #pragma unroll
            for (int i = 0; i < NDIMS; ++i)
                acc[i] = fmaf(RT[k * RT_STRIDE + i], xv, acc[i]);
        }
        #pragma unroll
        for (int i = 0; i < NDIMS; ++i)
            out[(size_t)m * NDIMS * S + (size_t)i * S + c0] = acc[i];
    }
}

extern "C" void kernel_launch(void* const* d_in, const int* in_sizes, int n_in,
                              void* d_out, int out_size, void* d_ws, size_t ws_size,
                              hipStream_t stream) {
    const float* x      = (const float*)d_in[0];
    const float* angles = (const float*)d_in[1];
    const float* mus    = (const float*)d_in[2];
    float* out          = (float*)d_out;

    const int M = in_sizes[1] / NANG;              // 1024
    const int S = in_sizes[0] / (M * NDIMS);       // 2048

    const size_t rt_bytes = (size_t)M * NDIMS * NDIMS * sizeof(float);  // 4 MB
    if (ws_size >= rt_bytes && (M % MPB) == 0 && (S % WCOLS) == 0) {
        float* RT = (float*)d_ws;
        gen_R<<<dim3(M / MPB), 256, 0, stream>>>(angles, mus, RT);
        dim3 grid(M, S / WCOLS);
        apply_R6<<<grid, 256, 0, stream>>>(x, RT, out, S);
    } else {
        soot_fused<<<dim3(M), 256, 0, stream>>>(x, angles, mus, out, S);
    }
}

// Round 10
// 187.770 us; speedup vs baseline: 9.3335x; 1.1447x over previous
//
#include <hip/hip_runtime.h>
#include <math.h>

#define NDIMS 32
#define NANG 496          // 32*31/2
#define MPB 8             // matrices per gen_R block
#define XCOLS 256         // columns per apply block

typedef float f32x4 __attribute__((ext_vector_type(4)));

// async 16B global -> LDS (dest: wave-uniform base + lane*16; src: per-lane)
__device__ __forceinline__ void load16_to_lds(const float* gsrc, float* ldst) {
    __builtin_amdgcn_global_load_lds(
        (const __attribute__((address_space(1))) void*)gsrc,
        (__attribute__((address_space(3))) void*)ldst,
        16, 0, 0);
}

// ---------------- Kernel 1: build R^T (mus folded) into workspace ----------
// RTbuf[m][k][i] = mus[m][i] * R[i][k]   ([k][i] layout)
__global__ __launch_bounds__(256)
void gen_R(const float* __restrict__ angles, const float* __restrict__ mus,
           float* __restrict__ RT)
{
    __shared__ float2 cs[MPB][NANG];      // 31744 B
    const int tid = threadIdx.x;
    const int m0  = blockIdx.x * MPB;

    for (int idx = tid; idx < MPB * NANG; idx += 256) {
        const int lm = idx / NANG, a = idx - lm * NANG;
        float sv, cv;
        sincosf(angles[(size_t)(m0 + lm) * NANG + a], &sv, &cv);
        cs[lm][a] = make_float2(cv, sv);
    }
    __syncthreads();

    const int lm = tid >> 5, j = tid & 31;   // lane j owns column j of mat[m]
    const int m  = m0 + lm;

    float r[NDIMS];
    #pragma unroll
    for (int i = 0; i < NDIMS; ++i) r[i] = (i == j) ? 1.0f : 0.0f;

    int sidx = 0;
    #pragma unroll
    for (int t = 0; t < NDIMS - 1; ++t) {
        #pragma unroll
        for (int b = t + 1; b < NDIMS; ++b) {
            const float2 v = cs[lm][sidx]; ++sidx;   // compile-time sidx
            const float c = v.x, sn = v.y;
            const float vt = r[t], vb = r[b];
            const float u  = sn * (vt + vb);
            r[t] = (c + sn) * vt - u;
            r[b] = (c - sn) * vb + u;
        }
    }

    // RT[m][k=j][i] = r[i] * mu[i]
    float* dst = RT + (size_t)m * (NDIMS * NDIMS) + (size_t)j * NDIMS;
    const float* mu = mus + (size_t)m * NDIMS;
    #pragma unroll
    for (int i = 0; i < NDIMS; i += 4) {
        f32x4 v;
        v.x = r[i + 0] * mu[i + 0];
        v.y = r[i + 1] * mu[i + 1];
        v.z = r[i + 2] * mu[i + 2];
        v.w = r[i + 3] * mu[i + 3];
        *reinterpret_cast<f32x4*>(dst + i) = v;
    }
}

// ---------------- Kernel 2: out = R*x with LDS-staged x --------------------
// R8/R9 post-mortem: ANY structure keeping in-flight x loads in VGPRs next
// to a 32-reg accumulator blows up to 176-184 VGPR (materialized per-lane
// addresses) -> 1-2 waves/SIMD -> latency never hidden. Fix: x never touches
// VGPRs on the way in -- global_load_lds direct to LDS. Per-thread state is
// just acc[8] + temps (~70 VGPR). Latency hidden by 4 resident blocks/CU
// (LDS 36 KB/block): block n computes while n+1..n+3 stage.
__global__ __launch_bounds__(256)
void apply_R7(const float* __restrict__ x, const float* __restrict__ RT,
              float* __restrict__ out, int S)
{
    __shared__ float rt[NDIMS * NDIMS];   // [k][i], 4 KB
    __shared__ float xt[NDIMS][XCOLS];    // [k][col], 32 KB

    const int tid  = threadIdx.x;
    const int m    = blockIdx.x;
    const int wid  = tid >> 6;            // wave id, 0..3
    const int lane = tid & 63;
    const int col0 = blockIdx.y * XCOLS;

    const float* __restrict__ xm = x   + (size_t)m * NDIMS * S + col0;
    float*       __restrict__ om = out + (size_t)m * NDIMS * S + col0;

    // stage R^T (4 KB): 256 threads x 16 B
    *reinterpret_cast<f32x4*>(&rt[tid * 4]) =
        *reinterpret_cast<const f32x4*>(RT + (size_t)m * (NDIMS * NDIMS) + tid * 4);

    // stage x tile (32 KB) async: wave wid stages rows k = c*4 + wid.
    // One instr stages one full row: lds dest = &xt[k][0] (wave-uniform,
    // HW adds lane*16), global src = xm + k*S + lane*4 (per-lane).
    #pragma unroll
    for (int c = 0; c < 8; ++c) {
        const int k = c * 4 + wid;
        load16_to_lds(xm + (size_t)k * S + lane * 4, &xt[k][0]);
    }
    __syncthreads();   // drains vmcnt+lgkmcnt before barrier

    const int i0 = wid * 8;               // this wave's 8 output rows

    f32x4 acc[8];
    #pragma unroll
    for (int r = 0; r < 8; ++r) acc[r] = (f32x4)0.0f;

    #pragma unroll
    for (int k = 0; k < NDIMS; ++k) {
        const f32x4 xv = *reinterpret_cast<const f32x4*>(&xt[k][lane * 4]); // lane-unique b128
        const f32x4 ra = *reinterpret_cast<const f32x4*>(&rt[k * NDIMS + i0]);     // broadcast
        const f32x4 rb = *reinterpret_cast<const f32x4*>(&rt[k * NDIMS + i0 + 4]); // broadcast
        #pragma unroll
        for (int r = 0; r < 4; ++r) {
            const float rv = (r == 0) ? ra.x : (r == 1) ? ra.y : (r == 2) ? ra.z : ra.w;
            acc[r].x = fmaf(rv, xv.x, acc[r].x);
            acc[r].y = fmaf(rv, xv.y, acc[r].y);
            acc[r].z = fmaf(rv, xv.z, acc[r].z);
            acc[r].w = fmaf(rv, xv.w, acc[r].w);
        }
        #pragma unroll
        for (int r = 0; r < 4; ++r) {
            const float rv = (r == 0) ? rb.x : (r == 1) ? rb.y : (r == 2) ? rb.z : rb.w;
            acc[r + 4].x = fmaf(rv, xv.x, acc[r + 4].x);
            acc[r + 4].y = fmaf(rv, xv.y, acc[r + 4].y);
            acc[r + 4].z = fmaf(rv, xv.z, acc[r + 4].z);
            acc[r + 4].w = fmaf(rv, xv.w, acc[r + 4].w);
        }
    }

    #pragma unroll
    for (int r = 0; r < 8; ++r)
        *reinterpret_cast<f32x4*>(om + (size_t)(i0 + r) * S + lane * 4) = acc[r];
}

// ---------------- Fallback: fused kernel (odd sizes / tiny ws) -------------
#define RT_STRIDE 36
__global__ __launch_bounds__(256, 4)
void soot_fused(const float* __restrict__ x, const float* __restrict__ angles,
                const float* __restrict__ mus, float* __restrict__ out, int S)
{
    __shared__ float2 cs[NANG];
    __shared__ float  RT[NDIMS * RT_STRIDE];
    const int tid = threadIdx.x;
    const int m   = blockIdx.x;

    for (int s0 = tid; s0 < NANG; s0 += 256) {
        float sv, cv;
        sincosf(angles[(size_t)m * NANG + s0], &sv, &cv);
        cs[s0] = make_float2(cv, sv);
    }
    __syncthreads();

    if (tid < NDIMS) {
        const int j = tid;
        float r[NDIMS];
        #pragma unroll
        for (int i = 0; i < NDIMS; ++i) r[i] = (i == j) ? 1.0f : 0.0f;
        int sidx = 0;
        #pragma unroll
        for (int t = 0; t < NDIMS - 1; ++t)
            #pragma unroll
            for (int b = t + 1; b < NDIMS; ++b) {
                const float2 v = cs[sidx]; ++sidx;
                const float c = v.x, sn = v.y;
                const float vt = r[t], vb = r[b];
                const float u  = sn * (vt + vb);
                r[t] = (c + sn) * vt - u;
                r[b] = (c - sn) * vb + u;
            }
        #pragma unroll
        for (int i = 0; i < NDIMS; ++i)
            RT[j * RT_STRIDE + i] = r[i] * mus[(size_t)m * NDIMS + i];
    }
    __syncthreads();

    for (int c0 = tid; c0 < S; c0 += 256) {
        float acc[NDIMS];
        #pragma unroll
        for (int i = 0; i < NDIMS; ++i) acc[i] = 0.f;
        #pragma unroll
        for (int k = 0; k < NDIMS; ++k) {
            const float xv = x[(size_t)m * NDIMS * S + (size_t)k * S + c0];
            #pragma unroll
            for (int i = 0; i < NDIMS; ++i)
                acc[i] = fmaf(RT[k * RT_STRIDE + i], xv, acc[i]);
        }
        #pragma unroll
        for (int i = 0; i < NDIMS; ++i)
            out[(size_t)m * NDIMS * S + (size_t)i * S + c0] = acc[i];
    }
}

extern "C" void kernel_launch(void* const* d_in, const int* in_sizes, int n_in,
                              void* d_out, int out_size, void* d_ws, size_t ws_size,
                              hipStream_t stream) {
    const float* x      = (const float*)d_in[0];
    const float* angles = (const float*)d_in[1];
    const float* mus    = (const float*)d_in[2];
    float* out          = (float*)d_out;

    const int M = in_sizes[1] / NANG;              // 1024
    const int S = in_sizes[0] / (M * NDIMS);       // 2048

    const size_t rt_bytes = (size_t)M * NDIMS * NDIMS * sizeof(float);  // 4 MB
    if (ws_size >= rt_bytes && (M % MPB) == 0 && (S % XCOLS) == 0) {
        float* RT = (float*)d_ws;
        gen_R<<<dim3(M / MPB), 256, 0, stream>>>(angles, mus, RT);
        dim3 grid(M, S / XCOLS);
        apply_R7<<<grid, 256, 0, stream>>>(x, RT, out, S);
    } else {
        soot_fused<<<dim3(M), 256, 0, stream>>>(x, angles, mus, out, S);
    }
}

// Round 11
// 147.835 us; speedup vs baseline: 11.8548x; 1.2701x over previous
//
#include <hip/hip_runtime.h>
#include <math.h>

#define NDIMS 32
#define NANG 496          // 32*31/2
#define MPB 8             // matrices per gen_R block
#define XCOLS 256         // columns per apply block

typedef float f32x4 __attribute__((ext_vector_type(4)));

// async 16B global -> LDS (dest: wave-uniform base + lane*16; src: per-lane)
__device__ __forceinline__ void load16_to_lds(const float* gsrc, float* ldst) {
    __builtin_amdgcn_global_load_lds(
        (const __attribute__((address_space(1))) void*)gsrc,
        (__attribute__((address_space(3))) void*)ldst,
        16, 0, 0);
}

// ---------------- Kernel 1: build R^T (mus folded) into workspace ----------
// RTbuf[m][k][i] = mus[m][i] * R[i][k]   ([k][i] layout)
__global__ __launch_bounds__(256)
void gen_R(const float* __restrict__ angles, const float* __restrict__ mus,
           float* __restrict__ RT)
{
    __shared__ float2 cs[MPB][NANG];      // 31744 B
    const int tid = threadIdx.x;
    const int m0  = blockIdx.x * MPB;

    for (int idx = tid; idx < MPB * NANG; idx += 256) {
        const int lm = idx / NANG, a = idx - lm * NANG;
        float sv, cv;
        sincosf(angles[(size_t)(m0 + lm) * NANG + a], &sv, &cv);
        cs[lm][a] = make_float2(cv, sv);
    }
    __syncthreads();

    const int lm = tid >> 5, j = tid & 31;   // lane j owns column j of mat[m]
    const int m  = m0 + lm;

    float r[NDIMS];
    #pragma unroll
    for (int i = 0; i < NDIMS; ++i) r[i] = (i == j) ? 1.0f : 0.0f;

    int sidx = 0;
    #pragma unroll
    for (int t = 0; t < NDIMS - 1; ++t) {
        #pragma unroll
        for (int b = t + 1; b < NDIMS; ++b) {
            const float2 v = cs[lm][sidx]; ++sidx;   // compile-time sidx
            const float c = v.x, sn = v.y;
            const float vt = r[t], vb = r[b];
            const float u  = sn * (vt + vb);
            r[t] = (c + sn) * vt - u;
            r[b] = (c - sn) * vb + u;
        }
    }

    // RT[m][k=j][i] = r[i] * mu[i]
    float* dst = RT + (size_t)m * (NDIMS * NDIMS) + (size_t)j * NDIMS;
    const float* mu = mus + (size_t)m * NDIMS;
    #pragma unroll
    for (int i = 0; i < NDIMS; i += 4) {
        f32x4 v;
        v.x = r[i + 0] * mu[i + 0];
        v.y = r[i + 1] * mu[i + 1];
        v.z = r[i + 2] * mu[i + 2];
        v.w = r[i + 3] * mu[i + 3];
        *reinterpret_cast<f32x4*>(dst + i) = v;
    }
}

// ---------------- Kernel 2: out = R*x with LDS-staged x --------------------
// R10 post-mortem: fully-unrolled k-loop let the scheduler hoist ~32
// ds_read_b128 destinations -> VGPR=196 -> 2 waves/SIMD -> 2 blocks/CU ->
// staging latency exposed. Fix: (a) hard cap VGPR at 128 via
// __launch_bounds__(256,2) [rolled-loop natural need ~70, so no spill,
// unlike R7's pipelined variant], (b) #pragma unroll 4 on the k-loop so
// hoisting is bounded to a 4-iteration window. Target: 4 waves/SIMD,
// 4 blocks/CU (LDS 36 KB/block = 144 KB), 3 blocks staging behind 1
// computing -> staging fully overlapped.
__global__ __launch_bounds__(256, 2)
void apply_R8(const float* __restrict__ x, const float* __restrict__ RT,
              float* __restrict__ out, int S)
{
    __shared__ float rt[NDIMS * NDIMS];   // [k][i], 4 KB
    __shared__ float xt[NDIMS][XCOLS];    // [k][col], 32 KB

    const int tid  = threadIdx.x;
    const int m    = blockIdx.x;
    const int wid  = tid >> 6;            // wave id, 0..3
    const int lane = tid & 63;
    const int col0 = blockIdx.y * XCOLS;

    const float* __restrict__ xm = x   + (size_t)m * NDIMS * S + col0;
    float*       __restrict__ om = out + (size_t)m * NDIMS * S + col0;

    // stage R^T (4 KB): 256 threads x 16 B
    *reinterpret_cast<f32x4*>(&rt[tid * 4]) =
        *reinterpret_cast<const f32x4*>(RT + (size_t)m * (NDIMS * NDIMS) + tid * 4);

    // stage x tile (32 KB) async: wave wid stages rows k = c*4 + wid.
    // One instr stages one full 1KB row: lds dest = &xt[k][0] (wave-uniform,
    // HW adds lane*16), global src = xm + k*S + lane*4 (per-lane).
    #pragma unroll
    for (int c = 0; c < 8; ++c) {
        const int k = c * 4 + wid;
        load16_to_lds(xm + (size_t)k * S + lane * 4, &xt[k][0]);
    }
    __syncthreads();   // drains vmcnt+lgkmcnt before barrier

    const int i0 = wid * 8;               // this wave's 8 output rows

    f32x4 acc[8];
    #pragma unroll
    for (int r = 0; r < 8; ++r) acc[r] = (f32x4)0.0f;

    #pragma unroll 4
    for (int k = 0; k < NDIMS; ++k) {
        const f32x4 xv = *reinterpret_cast<const f32x4*>(&xt[k][lane * 4]); // lane-unique b128
        const f32x4 ra = *reinterpret_cast<const f32x4*>(&rt[k * NDIMS + i0]);     // broadcast
        const f32x4 rb = *reinterpret_cast<const f32x4*>(&rt[k * NDIMS + i0 + 4]); // broadcast
        #pragma unroll
        for (int r = 0; r < 4; ++r) {
            const float rv = (r == 0) ? ra.x : (r == 1) ? ra.y : (r == 2) ? ra.z : ra.w;
            acc[r].x = fmaf(rv, xv.x, acc[r].x);
            acc[r].y = fmaf(rv, xv.y, acc[r].y);
            acc[r].z = fmaf(rv, xv.z, acc[r].z);
            acc[r].w = fmaf(rv, xv.w, acc[r].w);
        }
        #pragma unroll
        for (int r = 0; r < 4; ++r) {
            const float rv = (r == 0) ? rb.x : (r == 1) ? rb.y : (r == 2) ? rb.z : rb.w;
            acc[r + 4].x = fmaf(rv, xv.x, acc[r + 4].x);
            acc[r + 4].y = fmaf(rv, xv.y, acc[r + 4].y);
            acc[r + 4].z = fmaf(rv, xv.z, acc[r + 4].z);
            acc[r + 4].w = fmaf(rv, xv.w, acc[r + 4].w);
        }
    }

    #pragma unroll
    for (int r = 0; r < 8; ++r)
        *reinterpret_cast<f32x4*>(om + (size_t)(i0 + r) * S + lane * 4) = acc[r];
}

// ---------------- Fallback: fused kernel (odd sizes / tiny ws) -------------
#define RT_STRIDE 36
__global__ __launch_bounds__(256, 4)
void soot_fused(const float* __restrict__ x, const float* __restrict__ angles,
                const float* __restrict__ mus, float* __restrict__ out, int S)
{
    __shared__ float2 cs[NANG];
    __shared__ float  RT[NDIMS * RT_STRIDE];
    const int tid = threadIdx.x;
    const int m   = blockIdx.x;

    for (int s0 = tid; s0 < NANG; s0 += 256) {
        float sv, cv;
        sincosf(angles[(size_t)m * NANG + s0], &sv, &cv);
        cs[s0] = make_float2(cv, sv);
    }
    __syncthreads();

    if (tid < NDIMS) {
        const int j = tid;
        float r[NDIMS];
        #pragma unroll
        for (int i = 0; i < NDIMS; ++i) r[i] = (i == j) ? 1.0f : 0.0f;
        int sidx = 0;
        #pragma unroll
        for (int t = 0; t < NDIMS - 1; ++t)
            #pragma unroll
            for (int b = t + 1; b < NDIMS; ++b) {
                const float2 v = cs[sidx]; ++sidx;
                const float c = v.x, sn = v.y;
                const float vt = r[t], vb = r[b];
                const float u  = sn * (vt + vb);
                r[t] = (c + sn) * vt - u;
                r[b] = (c - sn) * vb + u;
            }
        #pragma unroll
        for (int i = 0; i < NDIMS; ++i)
            RT[j * RT_STRIDE + i] = r[i] * mus[(size_t)m * NDIMS + i];
    }
    __syncthreads();

    for (int c0 = tid; c0 < S; c0 += 256) {
        float acc[NDIMS];
        #pragma unroll
        for (int i = 0; i < NDIMS; ++i) acc[i] = 0.f;
        #pragma unroll
        for (int k = 0; k < NDIMS; ++k) {
            const float xv = x[(size_t)m * NDIMS * S + (size_t)k * S + c0];
            #pragma unroll
            for (int i = 0; i < NDIMS; ++i)
                acc[i] = fmaf(RT[k * RT_STRIDE + i], xv, acc[i]);
        }
        #pragma unroll
        for (int i = 0; i < NDIMS; ++i)
            out[(size_t)m * NDIMS * S + (size_t)i * S + c0] = acc[i];
    }
}

extern "C" void kernel_launch(void* const* d_in, const int* in_sizes, int n_in,
                              void* d_out, int out_size, void* d_ws, size_t ws_size,
                              hipStream_t stream) {
    const float* x      = (const float*)d_in[0];
    const float* angles = (const float*)d_in[1];
    const float* mus    = (const float*)d_in[2];
    float* out          = (float*)d_out;

    const int M = in_sizes[1] / NANG;              // 1024
    const int S = in_sizes[0] / (M * NDIMS);       // 2048

    const size_t rt_bytes = (size_t)M * NDIMS * NDIMS * sizeof(float);  // 4 MB
    if (ws_size >= rt_bytes && (M % MPB) == 0 && (S % XCOLS) == 0) {
        float* RT = (float*)d_ws;
        gen_R<<<dim3(M / MPB), 256, 0, stream>>>(angles, mus, RT);
        dim3 grid(M, S / XCOLS);
        apply_R8<<<grid, 256, 0, stream>>>(x, RT, out, S);
    } else {
        soot_fused<<<dim3(M), 256, 0, stream>>>(x, angles, mus, out, S);
    }
}